// Round 8
// baseline (197.638 us; speedup 1.0000x reference)
//
#include <hip/hip_runtime.h>
#include <hip/hip_cooperative_groups.h>
#include <hip/hip_bf16.h>

namespace cg = cooperative_groups;

#define NUM_CAMS 6
#define NQ       40000
#define MAX_LEN  10000
#define ED       256
#define NBLK     ((NQ + 255) / 256)   // 157

typedef float f32x2 __attribute__((ext_vector_type(2)));

// d_out layout (float offsets)
#define OFF_IDX  0                                   // 6*10000
#define OFF_LEN  (NUM_CAMS * MAX_LEN)                // 60000, size 6
#define OFF_Q    (OFF_LEN + NUM_CAMS)                // 60006
#define OFF_REF  (OFF_Q + NUM_CAMS * MAX_LEN * ED)   // 15,420,006
#define OFF_CNT  (OFF_REF + NUM_CAMS * MAX_LEN * 8)  // 15,900,006

// ws layout (ints)
#define WS_OFF    0                               // [0, 942) per-(cam,block) valid counts
#define WS_MASK_I 960                             // u64 ballot masks, byte off 3840 (8B aligned)
#define WS_MASK_N (NUM_CAMS * NBLK * 4)           // 3768 u64 = 7536 ints
#define WS_LEN    (WS_MASK_I + 2 * WS_MASK_N)     // 8496, +6 per-cam len
#define WS_POS    (WS_LEN + 8)                    // 8504, +6*NQ q->pos table
#define WS_NEED_BYTES ((WS_POS + NUM_CAMS * NQ) * 4)

#define QBLOCKS      (NQ / 4)                       // 10000 q-group items (4 q each)
#define TAIL_BLOCKS  (NUM_CAMS * MAX_LEN / 4)       // 15000 tail items (4 rows each)
#define GATHER_GRID  2048                           // persistent blocks (fallback kGatherQ)
#define CNT_BLOCKS   ((NQ + 255) / 256)             // 157 (fallback count_norm)
#define GATHER_BLOCKS (NUM_CAMS * MAX_LEN / 4)      // 15000 (fallback row-major)

// ---------------- fused cooperative kernel ----------------
// grid = (157, 6) x 256 threads. Phase 1: masks+counts (single bev pass).
// grid.sync. Phase 2: offsets -> idx/pos/len + count_norm from masks.
// grid.sync. Phase 3: grid-stride q-major multicast gather + tail zero.
__global__ __launch_bounds__(256) void kFused(const float* __restrict__ query,
                                              const float* __restrict__ refp,
                                              const int* __restrict__ bev,
                                              float* __restrict__ out,
                                              int* __restrict__ ws) {
    cg::grid_group grid = cg::this_grid();
    const int blk  = blockIdx.x;   // 0..156
    const int cam  = blockIdx.y;   // 0..5
    const int tid  = threadIdx.x;
    const int lane = tid & 63;
    const int wave = tid >> 6;
    unsigned long long* wsm = reinterpret_cast<unsigned long long*>(ws + WS_MASK_I);

    // ---- Phase 1 ----
    const int q = blk * 256 + tid;
    bool v = false;
    if (q < NQ) {
        const int4 m = *reinterpret_cast<const int4*>(bev + ((size_t)cam * NQ + q) * 4);
        v = (m.x > 0) | (m.y > 0) | (m.z > 0) | (m.w > 0);
    }
    const unsigned long long bal = __ballot(v);
    __shared__ int wsum[4];
    if (lane == 0) {
        wsum[wave] = __popcll(bal);
        wsm[((size_t)cam * NBLK + blk) * 4 + wave] = bal;
    }
    __syncthreads();
    if (tid == 0)
        ws[WS_OFF + cam * NBLK + blk] = wsum[0] + wsum[1] + wsum[2] + wsum[3];

    grid.sync();

    // ---- Phase 2 ----
    const int part = (tid < NBLK) ? ws[WS_OFF + cam * NBLK + tid] : 0;
    int t = part;                       // total over all blocks
    int o = (tid < blk) ? part : 0;     // exclusive offset for this block
    #pragma unroll
    for (int d = 1; d < 64; d <<= 1) {
        t += __shfl_xor(t, d, 64);
        o += __shfl_xor(o, d, 64);
    }
    __shared__ int sT[4], sO[4];
    if (lane == 0) { sT[wave] = t; sO[wave] = o; }
    __syncthreads();
    const int total    = sT[0] + sT[1] + sT[2] + sT[3];
    const int blockOff = sO[0] + sO[1] + sO[2] + sO[3];

    if (blk == 0 && tid == 0) {
        const int len = total < MAX_LEN ? total : MAX_LEN;
        ws[WS_LEN + cam] = len;
        out[OFF_LEN + cam] = (float)len;
    }
    if (q < NQ) {
        int waveOff = 0;                 // wsum[] still holds phase-1 per-wave popcounts
        #pragma unroll
        for (int w = 0; w < 4; ++w)
            if (w < wave) waveOff += wsum[w];
        const int prefix = __popcll(bal & ((1ull << lane) - 1ull));
        const int vb  = blockOff + waveOff + prefix;      // valid strictly before q
        const int pos = v ? vb : (total + (q - vb));      // stable partition position
        if (pos < MAX_LEN) out[OFF_IDX + cam * MAX_LEN + pos] = (float)q;
        ws[WS_POS + cam * NQ + q] = (v && vb < MAX_LEN) ? vb : -1;
    }
    if (cam == 0 && q < NQ) {            // count_norm from the 6 stored masks
        int cnt = 0;
        #pragma unroll
        for (int c = 0; c < NUM_CAMS; ++c) {
            const unsigned long long m = wsm[((size_t)c * NBLK + blk) * 4 + wave];
            cnt += (int)((m >> lane) & 1ull);
        }
        out[OFF_CNT + q] = 1.0f / fmaxf((float)cnt, 1.0f);
    }

    grid.sync();

    // ---- Phase 3 ----
    const int bid = blockIdx.y * gridDim.x + blockIdx.x;  // 0..941
    const int nb  = gridDim.x * gridDim.y;                // 942
    const int group = wave;
    for (int item = bid; item < QBLOCKS + TAIL_BLOCKS; item += nb) {
        if (item < QBLOCKS) {
            const int qq = item * 4 + group;   // < NQ
            int pos[NUM_CAMS];
            bool any = false;
            #pragma unroll
            for (int c = 0; c < NUM_CAMS; ++c) {
                const int p = ws[WS_POS + c * NQ + qq];
                pos[c] = p;
                any |= (p >= 0);
            }
            if (!any) continue;

            const float4 vq = *reinterpret_cast<const float4*>(query + (size_t)qq * ED + lane * 4);
            f32x2 a; a.x = vq.x; a.y = vq.y;
            f32x2 b; b.x = vq.z; b.y = vq.w;

            #pragma unroll
            for (int c = 0; c < NUM_CAMS; ++c) {
                const int p = pos[c];
                if (p >= 0) {
                    f32x2* o2 = reinterpret_cast<f32x2*>(out + OFF_Q + ((size_t)c * MAX_LEN + p) * ED + lane * 4);
                    o2[0] = a;
                    o2[1] = b;
                    if (lane < 4) {
                        const f32x2 r = *reinterpret_cast<const f32x2*>(refp + ((size_t)c * NQ + qq) * 8 + lane * 2);
                        *reinterpret_cast<f32x2*>(out + OFF_REF + ((size_t)c * MAX_LEN + p) * 8 + lane * 2) = r;
                    }
                }
            }
        } else {
            const int rowId = (item - QBLOCKS) * 4 + group;
            const int c = rowId / MAX_LEN;
            const int j = rowId - c * MAX_LEN;
            if (j < ws[WS_LEN + c]) continue;
            const f32x2 z = (f32x2)(0.f);
            f32x2* o2 = reinterpret_cast<f32x2*>(out + OFF_Q + (size_t)rowId * ED + lane * 4);
            o2[0] = z; o2[1] = z;
            if (lane < 4)
                *reinterpret_cast<f32x2*>(out + OFF_REF + (size_t)rowId * 8 + lane * 2) = z;
        }
    }
}

// ---------------- fallback path (round-7 proven) ----------------
__global__ void kA_counts(const int* __restrict__ bev, float* __restrict__ out,
                          int* __restrict__ ws, int usePos) {
    __shared__ int cnt[NUM_CAMS];
    const int tid = threadIdx.x;
    const int blk = blockIdx.x;
    const int q   = blk * 256 + tid;
    if (tid < NUM_CAMS) cnt[tid] = 0;
    __syncthreads();
    const int lane = tid & 63;
    const int wave = tid >> 6;
    const bool inb = q < NQ;
    unsigned long long* wsm = reinterpret_cast<unsigned long long*>(ws + WS_MASK_I);
    int myCount = 0;
    #pragma unroll
    for (int cam = 0; cam < NUM_CAMS; ++cam) {
        bool v = false;
        if (inb) {
            const int4 m = *reinterpret_cast<const int4*>(bev + ((size_t)cam * NQ + q) * 4);
            v = (m.x > 0) | (m.y > 0) | (m.z > 0) | (m.w > 0);
        }
        myCount += v ? 1 : 0;
        const unsigned long long bal = __ballot(v);
        if (lane == 0) {
            atomicAdd(&cnt[cam], __popcll(bal));
            if (usePos) wsm[((size_t)cam * NBLK + blk) * 4 + wave] = bal;
        }
    }
    if (inb) out[OFF_CNT + q] = 1.0f / fmaxf((float)myCount, 1.0f);
    __syncthreads();
    if (tid < NUM_CAMS) ws[WS_OFF + tid * NBLK + blk] = cnt[tid];
}

__global__ void kBC_indexes(const int* __restrict__ bev, float* __restrict__ out,
                            int* __restrict__ ws, int usePos) {
    const int blk = blockIdx.x;
    const int cam = blockIdx.y;
    const int tid = threadIdx.x;
    const int lane = tid & 63;
    const int wave = tid >> 6;

    const int part = (tid < NBLK) ? ws[WS_OFF + cam * NBLK + tid] : 0;
    int t = part;
    int o = (tid < blk) ? part : 0;
    #pragma unroll
    for (int d = 1; d < 64; d <<= 1) {
        t += __shfl_xor(t, d, 64);
        o += __shfl_xor(o, d, 64);
    }
    __shared__ int sT[4], sO[4], waveSums[4];

    unsigned long long mask;
    if (usePos) {
        const unsigned long long* wsm =
            reinterpret_cast<const unsigned long long*>(ws + WS_MASK_I);
        mask = wsm[((size_t)cam * NBLK + blk) * 4 + wave];
    } else {
        const int q = blk * 256 + tid;
        bool v = false;
        if (q < NQ) {
            const int4 m = *reinterpret_cast<const int4*>(bev + ((size_t)cam * NQ + q) * 4);
            v = (m.x > 0) | (m.y > 0) | (m.z > 0) | (m.w > 0);
        }
        mask = __ballot(v);
    }
    if (lane == 0) { sT[wave] = t; sO[wave] = o; waveSums[wave] = __popcll(mask); }
    __syncthreads();
    const int total    = sT[0] + sT[1] + sT[2] + sT[3];
    const int blockOff = sO[0] + sO[1] + sO[2] + sO[3];

    if (blk == 0 && tid == 0) {
        const int len = total < MAX_LEN ? total : MAX_LEN;
        ws[WS_LEN + cam] = len;
        out[OFF_LEN + cam] = (float)len;
    }

    const int q = blk * 256 + tid;
    if (q < NQ) {
        int waveOff = 0;
        #pragma unroll
        for (int w = 0; w < 4; ++w)
            if (w < wave) waveOff += waveSums[w];
        const bool v     = (mask >> lane) & 1ull;
        const int prefix = __popcll(mask & ((1ull << lane) - 1ull));
        const int vb  = blockOff + waveOff + prefix;
        const int pos = v ? vb : (total + (q - vb));
        if (pos < MAX_LEN) out[OFF_IDX + cam * MAX_LEN + pos] = (float)q;
        if (usePos) ws[WS_POS + cam * NQ + q] = (v && vb < MAX_LEN) ? vb : -1;
    }
}

__global__ void kGatherQ(const float* __restrict__ query, const float* __restrict__ refp,
                         float* __restrict__ out, const int* __restrict__ ws) {
    const int tid   = threadIdx.x;
    const int group = tid >> 6;
    const int lane  = tid & 63;
    for (int item = blockIdx.x; item < QBLOCKS + TAIL_BLOCKS; item += gridDim.x) {
        if (item < QBLOCKS) {
            const int q = item * 4 + group;
            int pos[NUM_CAMS];
            bool any = false;
            #pragma unroll
            for (int cam = 0; cam < NUM_CAMS; ++cam) {
                const int p = ws[WS_POS + cam * NQ + q];
                pos[cam] = p;
                any |= (p >= 0);
            }
            if (!any) continue;

            const float4 vq = *reinterpret_cast<const float4*>(query + (size_t)q * ED + lane * 4);
            f32x2 a; a.x = vq.x; a.y = vq.y;
            f32x2 b; b.x = vq.z; b.y = vq.w;

            #pragma unroll
            for (int cam = 0; cam < NUM_CAMS; ++cam) {
                const int p = pos[cam];
                if (p >= 0) {
                    f32x2* o2 = reinterpret_cast<f32x2*>(out + OFF_Q + ((size_t)cam * MAX_LEN + p) * ED + lane * 4);
                    o2[0] = a;
                    o2[1] = b;
                    if (lane < 4) {
                        const f32x2 r = *reinterpret_cast<const f32x2*>(refp + ((size_t)cam * NQ + q) * 8 + lane * 2);
                        *reinterpret_cast<f32x2*>(out + OFF_REF + ((size_t)cam * MAX_LEN + p) * 8 + lane * 2) = r;
                    }
                }
            }
        } else {
            const int rowId = (item - QBLOCKS) * 4 + group;
            const int cam   = rowId / MAX_LEN;
            const int j     = rowId - cam * MAX_LEN;
            if (j < ws[WS_LEN + cam]) continue;
            const f32x2 z = (f32x2)(0.f);
            f32x2* o2 = reinterpret_cast<f32x2*>(out + OFF_Q + (size_t)rowId * ED + lane * 4);
            o2[0] = z; o2[1] = z;
            if (lane < 4)
                *reinterpret_cast<f32x2*>(out + OFF_REF + (size_t)rowId * 8 + lane * 2) = z;
        }
    }
}

__global__ void kGather(const float* __restrict__ query, const float* __restrict__ refp,
                        float* __restrict__ out, const int* __restrict__ ws,
                        const int* __restrict__ bev) {
    const int blk = blockIdx.x;
    const int tid = threadIdx.x;
    if (blk >= GATHER_BLOCKS) {
        const int q = (blk - GATHER_BLOCKS) * 256 + tid;
        if (q < NQ) {
            int cnt = 0;
            #pragma unroll
            for (int cam = 0; cam < NUM_CAMS; ++cam) {
                const int4 m = *reinterpret_cast<const int4*>(bev + ((size_t)cam * NQ + q) * 4);
                cnt += ((m.x > 0) | (m.y > 0) | (m.z > 0) | (m.w > 0)) ? 1 : 0;
            }
            out[OFF_CNT + q] = 1.0f / fmaxf((float)cnt, 1.0f);
        }
        return;
    }
    const int rowId = blk * 4 + (tid >> 6);
    const int lane  = tid & 63;
    const int cam   = rowId / MAX_LEN;
    const int j     = rowId - cam * MAX_LEN;
    const int len   = ws[WS_LEN + cam];

    f32x2 a = (f32x2)(0.f), b = (f32x2)(0.f), r0 = (f32x2)(0.f), r1 = (f32x2)(0.f);
    if (j < len) {
        const int idx = (int)out[OFF_IDX + cam * MAX_LEN + j];
        const float4 vq = *reinterpret_cast<const float4*>(query + (size_t)idx * ED + lane * 4);
        a.x = vq.x; a.y = vq.y;
        b.x = vq.z; b.y = vq.w;
        if (lane < 2) {
            const float4 r = *reinterpret_cast<const float4*>(refp + ((size_t)cam * NQ + idx) * 8 + lane * 4);
            r0.x = r.x; r0.y = r.y;
            r1.x = r.z; r1.y = r.w;
        }
    }
    f32x2* o2 = reinterpret_cast<f32x2*>(out + OFF_Q + (size_t)rowId * ED + lane * 4);
    o2[0] = a;
    o2[1] = b;
    if (lane < 2) {
        f32x2* r2 = reinterpret_cast<f32x2*>(out + OFF_REF + (size_t)rowId * 8 + lane * 4);
        r2[0] = r0;
        r2[1] = r1;
    }
}

extern "C" void kernel_launch(void* const* d_in, const int* in_sizes, int n_in,
                              void* d_out, int out_size, void* d_ws, size_t ws_size,
                              hipStream_t stream) {
    const float* query = (const float*)d_in[0];
    const float* refp  = (const float*)d_in[1];
    const int*   bev   = (const int*)d_in[2];
    float* out = (float*)d_out;
    int*   ws  = (int*)d_ws;
    const int usePos = (ws_size >= (size_t)WS_NEED_BYTES) ? 1 : 0;

    if (usePos) {
        void* args[] = {(void*)&query, (void*)&refp, (void*)&bev, (void*)&out, (void*)&ws};
        hipError_t err = hipLaunchCooperativeKernel(
            reinterpret_cast<void*>(kFused), dim3(NBLK, NUM_CAMS), dim3(256),
            args, 0, stream);
        if (err == hipSuccess) return;
        (void)hipGetLastError();  // clear sticky error, fall through
    }

    kA_counts<<<NBLK, 256, 0, stream>>>(bev, out, ws, usePos);
    kBC_indexes<<<dim3(NBLK, NUM_CAMS), 256, 0, stream>>>(bev, out, ws, usePos);
    if (usePos) {
        kGatherQ<<<GATHER_GRID, 256, 0, stream>>>(query, refp, out, ws);
    } else {
        kGather<<<GATHER_BLOCKS + CNT_BLOCKS, 256, 0, stream>>>(query, refp, out, ws, bev);
    }
}

// Round 9
// 46.005 us; speedup vs baseline: 4.2960x; 4.2960x over previous
//
#include <hip/hip_runtime.h>
#include <hip/hip_bf16.h>

#define NUM_CAMS 6
#define NQ       40000
#define MAX_LEN  10000
#define ED       256
#define NBLK     ((NQ + 255) / 256)   // 157

typedef float f32x2 __attribute__((ext_vector_type(2)));
typedef unsigned long long u64;

// d_out layout (float offsets)
#define OFF_IDX  0                                   // 6*10000
#define OFF_LEN  (NUM_CAMS * MAX_LEN)                // 60000, size 6
#define OFF_Q    (OFF_LEN + NUM_CAMS)                // 60006
#define OFF_REF  (OFF_Q + NUM_CAMS * MAX_LEN * ED)   // 15,420,006
#define OFF_CNT  (OFF_REF + NUM_CAMS * MAX_LEN * 8)  // 15,900,006

// ws layout (ints) — new 2-kernel path
#define WS_CNT    0                               // [0, 942) per-(cam,block) valid counts
#define WS_MASK_I 960                             // u64 masks at byte 3840 (32B aligned)
#define WS_MASK_INTS (NUM_CAMS * NBLK * 4 * 2)    // 3768 u64 = 7536 ints
#define WS_NEED_BYTES ((WS_MASK_I + WS_MASK_INTS) * 4)
// fallback extras
#define FB_LEN    (WS_MASK_I + WS_MASK_INTS)      // +6 per-cam len

#define QBLOCKS      (NQ / 4)                     // 10000 q-items (4 q each)
#define TAIL_BLOCKS  (NUM_CAMS * MAX_LEN / 4)     // 15000 tail items (4 rows each)
#define ALL_GRID     2048
#define GATHER_BLOCKS (NUM_CAMS * MAX_LEN / 4)    // 15000 (fallback row-major)
#define CNT_BLOCKS   NBLK

// 157 blocks: one bev pass -> per-(cam,block) counts + ballot masks + count_norm.
__global__ void kMeta(const int* __restrict__ bev, float* __restrict__ out,
                      int* __restrict__ ws) {
    __shared__ int cnt[NUM_CAMS];
    const int tid = threadIdx.x;
    const int blk = blockIdx.x;
    const int q   = blk * 256 + tid;
    if (tid < NUM_CAMS) cnt[tid] = 0;
    __syncthreads();
    const int lane = tid & 63;
    const int wave = tid >> 6;
    const bool inb = q < NQ;
    u64* wsm = reinterpret_cast<u64*>(ws + WS_MASK_I);
    int myCount = 0;
    #pragma unroll
    for (int cam = 0; cam < NUM_CAMS; ++cam) {
        bool v = false;
        if (inb) {
            const int4 m = *reinterpret_cast<const int4*>(bev + ((size_t)cam * NQ + q) * 4);
            v = (m.x > 0) | (m.y > 0) | (m.z > 0) | (m.w > 0);
        }
        myCount += v ? 1 : 0;
        const u64 bal = __ballot(v);
        if (lane == 0) {
            atomicAdd(&cnt[cam], __popcll(bal));
            wsm[((size_t)cam * NBLK + blk) * 4 + wave] = bal;
        }
    }
    if (inb) out[OFF_CNT + q] = 1.0f / fmaxf((float)myCount, 1.0f);
    __syncthreads();
    if (tid < NUM_CAMS) ws[WS_CNT + tid * NBLK + blk] = cnt[tid];
}

// 2048 persistent blocks. Prologue: scan 942 counts -> LDS exclusive offsets +
// totals/lens. Items [0,10000): derive per-cam rank from LDS offsets + u64
// masks, write indexes inline, q-major multicast gather (1KB query row read
// once, scattered to every selecting cam). Items [10000,25000): tail zeroing.
__global__ __launch_bounds__(256) void kAll(const float* __restrict__ query,
                                            const float* __restrict__ refp,
                                            float* __restrict__ out,
                                            const int* __restrict__ ws) {
    __shared__ int sOff[NUM_CAMS][NBLK + 3];
    __shared__ int sTot[NUM_CAMS], sLen[NUM_CAMS];
    const int tid  = threadIdx.x;
    const int lane = tid & 63;
    const int wave = tid >> 6;

    for (int cam = wave; cam < NUM_CAMS; cam += 4) {   // waves 0-3 cover 6 cams
        int running = 0;
        for (int base = 0; base < NBLK; base += 64) {
            const int i = base + lane;
            const int val = (i < NBLK) ? ws[WS_CNT + cam * NBLK + i] : 0;
            int v = val;
            #pragma unroll
            for (int d = 1; d < 64; d <<= 1) {
                const int n = __shfl_up(v, d, 64);
                if (lane >= d) v += n;
            }
            if (i < NBLK) sOff[cam][i] = running + v - val;   // exclusive
            running += __shfl(v, 63, 64);
        }
        if (lane == 0) {
            sTot[cam] = running;
            sLen[cam] = running < MAX_LEN ? running : MAX_LEN;
        }
    }
    __syncthreads();
    if (blockIdx.x == 0 && tid < NUM_CAMS) out[OFF_LEN + tid] = (float)sLen[tid];

    const u64* __restrict__ wsm = reinterpret_cast<const u64*>(ws + WS_MASK_I);

    for (int item = blockIdx.x; item < QBLOCKS + TAIL_BLOCKS; item += gridDim.x) {
        if (item < QBLOCKS) {
            const int q  = item * 4 + wave;          // < NQ
            const int qb = q >> 8;
            const int qw = (q >> 6) & 3;
            const int ql = q & 63;
            int pos[NUM_CAMS];
            bool any = false;
            #pragma unroll
            for (int c = 0; c < NUM_CAMS; ++c) {
                const u64* mp = wsm + ((size_t)c * NBLK + qb) * 4;
                const u64 m0 = mp[0], m1 = mp[1], m2 = mp[2], m3 = mp[3];
                const u64 mq = qw == 0 ? m0 : qw == 1 ? m1 : qw == 2 ? m2 : m3;
                int pre = 0;
                if (qw > 0) pre += __popcll(m0);
                if (qw > 1) pre += __popcll(m1);
                if (qw > 2) pre += __popcll(m2);
                const bool v  = (mq >> ql) & 1ull;
                const int  vb = sOff[c][qb] + pre + __popcll(mq & ((1ull << ql) - 1ull));
                pos[c] = (v && vb < MAX_LEN) ? vb : -1;
                any |= pos[c] >= 0;
                if (lane == 0) {                      // inline indexes write
                    if (v) {
                        if (vb < MAX_LEN) out[OFF_IDX + c * MAX_LEN + vb] = (float)q;
                    } else {
                        const int pi = sTot[c] + (q - vb);   // stable invalid tail
                        if (pi < MAX_LEN) out[OFF_IDX + c * MAX_LEN + pi] = (float)q;
                    }
                }
            }
            if (!any) continue;

            const float4 vq = *reinterpret_cast<const float4*>(query + (size_t)q * ED + lane * 4);
            f32x2 a; a.x = vq.x; a.y = vq.y;
            f32x2 b; b.x = vq.z; b.y = vq.w;

            #pragma unroll
            for (int c = 0; c < NUM_CAMS; ++c) {
                const int p = pos[c];
                if (p >= 0) {
                    f32x2* o2 = reinterpret_cast<f32x2*>(out + OFF_Q + ((size_t)c * MAX_LEN + p) * ED + lane * 4);
                    o2[0] = a;
                    o2[1] = b;
                    if (lane < 4) {
                        const f32x2 r = *reinterpret_cast<const f32x2*>(refp + ((size_t)c * NQ + q) * 8 + lane * 2);
                        *reinterpret_cast<f32x2*>(out + OFF_REF + ((size_t)c * MAX_LEN + p) * 8 + lane * 2) = r;
                    }
                }
            }
        } else {
            const int rowId = (item - QBLOCKS) * 4 + wave;
            const int c = rowId / MAX_LEN;
            const int j = rowId - c * MAX_LEN;
            if (j < sLen[c]) continue;
            const f32x2 z = (f32x2)(0.f);
            f32x2* o2 = reinterpret_cast<f32x2*>(out + OFF_Q + (size_t)rowId * ED + lane * 4);
            o2[0] = z; o2[1] = z;
            if (lane < 4)
                *reinterpret_cast<f32x2*>(out + OFF_REF + (size_t)rowId * 8 + lane * 2) = z;
        }
    }
}

// ---------------- fallback path (tiny ws; round-3 proven structure) ----------------
__global__ void kBC_fb(const int* __restrict__ bev, float* __restrict__ out,
                       int* __restrict__ ws) {
    const int blk = blockIdx.x;
    const int cam = blockIdx.y;
    const int tid = threadIdx.x;
    const int lane = tid & 63;
    const int wave = tid >> 6;

    const int part = (tid < NBLK) ? ws[WS_CNT + cam * NBLK + tid] : 0;
    int t = part;
    int o = (tid < blk) ? part : 0;
    #pragma unroll
    for (int d = 1; d < 64; d <<= 1) {
        t += __shfl_xor(t, d, 64);
        o += __shfl_xor(o, d, 64);
    }
    __shared__ int sT[4], sO[4], waveSums[4];

    const int q = blk * 256 + tid;
    bool v = false;
    if (q < NQ) {
        const int4 m = *reinterpret_cast<const int4*>(bev + ((size_t)cam * NQ + q) * 4);
        v = (m.x > 0) | (m.y > 0) | (m.z > 0) | (m.w > 0);
    }
    const u64 mask = __ballot(v);
    if (lane == 0) { sT[wave] = t; sO[wave] = o; waveSums[wave] = __popcll(mask); }
    __syncthreads();
    const int total    = sT[0] + sT[1] + sT[2] + sT[3];
    const int blockOff = sO[0] + sO[1] + sO[2] + sO[3];

    if (blk == 0 && tid == 0) {
        const int len = total < MAX_LEN ? total : MAX_LEN;
        ws[FB_LEN + cam] = len;
        out[OFF_LEN + cam] = (float)len;
    }
    if (q < NQ) {
        int waveOff = 0;
        #pragma unroll
        for (int w = 0; w < 4; ++w)
            if (w < wave) waveOff += waveSums[w];
        const int prefix = __popcll(mask & ((1ull << lane) - 1ull));
        const int vb  = blockOff + waveOff + prefix;
        const int pos = v ? vb : (total + (q - vb));
        if (pos < MAX_LEN) out[OFF_IDX + cam * MAX_LEN + pos] = (float)q;
    }
}

__global__ void kGather_fb(const float* __restrict__ query, const float* __restrict__ refp,
                           float* __restrict__ out, const int* __restrict__ ws) {
    const int rowId = blockIdx.x * 4 + (threadIdx.x >> 6);
    const int lane  = threadIdx.x & 63;
    const int cam   = rowId / MAX_LEN;
    const int j     = rowId - cam * MAX_LEN;
    const int len   = ws[FB_LEN + cam];

    f32x2 a = (f32x2)(0.f), b = (f32x2)(0.f), r0 = (f32x2)(0.f), r1 = (f32x2)(0.f);
    if (j < len) {
        const int idx = (int)out[OFF_IDX + cam * MAX_LEN + j];
        const float4 vq = *reinterpret_cast<const float4*>(query + (size_t)idx * ED + lane * 4);
        a.x = vq.x; a.y = vq.y;
        b.x = vq.z; b.y = vq.w;
        if (lane < 2) {
            const float4 r = *reinterpret_cast<const float4*>(refp + ((size_t)cam * NQ + idx) * 8 + lane * 4);
            r0.x = r.x; r0.y = r.y;
            r1.x = r.z; r1.y = r.w;
        }
    }
    f32x2* o2 = reinterpret_cast<f32x2*>(out + OFF_Q + (size_t)rowId * ED + lane * 4);
    o2[0] = a;
    o2[1] = b;
    if (lane < 2) {
        f32x2* r2 = reinterpret_cast<f32x2*>(out + OFF_REF + (size_t)rowId * 8 + lane * 4);
        r2[0] = r0;
        r2[1] = r1;
    }
}

extern "C" void kernel_launch(void* const* d_in, const int* in_sizes, int n_in,
                              void* d_out, int out_size, void* d_ws, size_t ws_size,
                              hipStream_t stream) {
    const float* query = (const float*)d_in[0];
    const float* refp  = (const float*)d_in[1];
    const int*   bev   = (const int*)d_in[2];
    float* out = (float*)d_out;
    int*   ws  = (int*)d_ws;

    kMeta<<<NBLK, 256, 0, stream>>>(bev, out, ws);
    if (ws_size >= (size_t)WS_NEED_BYTES + 64) {
        kAll<<<ALL_GRID, 256, 0, stream>>>(query, refp, out, ws);
    } else {
        kBC_fb<<<dim3(NBLK, NUM_CAMS), 256, 0, stream>>>(bev, out, ws);
        kGather_fb<<<GATHER_BLOCKS, 256, 0, stream>>>(query, refp, out, ws);
    }
}

// Round 10
// 31.903 us; speedup vs baseline: 6.1949x; 1.4420x over previous
//
#include <hip/hip_runtime.h>
#include <hip/hip_bf16.h>

#define NUM_CAMS 6
#define NQ       40000
#define MAX_LEN  10000
#define ED       256
#define NBLK     ((NQ + 255) / 256)   // 157

typedef float f32x2 __attribute__((ext_vector_type(2)));
typedef unsigned long long u64;

// d_out layout (float offsets)
#define OFF_IDX  0                                   // 6*10000
#define OFF_LEN  (NUM_CAMS * MAX_LEN)                // 60000, size 6
#define OFF_Q    (OFF_LEN + NUM_CAMS)                // 60006  (byte 240024 == 8 mod 16)
#define OFF_REF  (OFF_Q + NUM_CAMS * MAX_LEN * ED)   // 15,420,006
#define OFF_CNT  (OFF_REF + NUM_CAMS * MAX_LEN * 8)  // 15,900,006

// ws layout (ints)
#define WS_OFF    0                               // [0, 942) per-(cam,block) valid counts
#define WS_MASK_I 960                             // u64 ballot masks, byte off 3840 (8B aligned)
#define WS_MASK_N (NUM_CAMS * NBLK * 4)           // 3768 u64 = 7536 ints
#define WS_LEN    (WS_MASK_I + 2 * WS_MASK_N)     // 8496, +6 per-cam len
#define WS_POS    (WS_LEN + 8)                    // 8504, +6*NQ q->pos table
#define WS_NEED_BYTES ((WS_POS + NUM_CAMS * NQ) * 4)

#define QBLOCKS      (NQ / 4)                       // 10000 q-items (4 q each)
#define TAIL_BLOCKS  (NUM_CAMS * MAX_LEN / 4)       // 15000 tail items (4 rows each)
#define GATHER_GRID  2048                           // persistent blocks for kGatherQ
#define CNT_BLOCKS   ((NQ + 255) / 256)             // 157 (fallback count_norm)
#define GATHER_BLOCKS (NUM_CAMS * MAX_LEN / 4)      // 15000 (fallback row-major)

// 157 blocks: per-(block,cam) valid counts + ballot masks + fused count_norm.
__global__ void kA_counts(const int* __restrict__ bev, float* __restrict__ out,
                          int* __restrict__ ws, int usePos) {
    __shared__ int cnt[NUM_CAMS];
    const int tid = threadIdx.x;
    const int blk = blockIdx.x;
    const int q   = blk * 256 + tid;
    if (tid < NUM_CAMS) cnt[tid] = 0;
    __syncthreads();
    const int lane = tid & 63;
    const int wave = tid >> 6;
    const bool inb = q < NQ;
    u64* wsm = reinterpret_cast<u64*>(ws + WS_MASK_I);
    int myCount = 0;
    #pragma unroll
    for (int cam = 0; cam < NUM_CAMS; ++cam) {
        bool v = false;
        if (inb) {
            const int4 m = *reinterpret_cast<const int4*>(bev + ((size_t)cam * NQ + q) * 4);
            v = (m.x > 0) | (m.y > 0) | (m.z > 0) | (m.w > 0);
        }
        myCount += v ? 1 : 0;
        const u64 bal = __ballot(v);
        if (lane == 0) {
            atomicAdd(&cnt[cam], __popcll(bal));
            if (usePos) wsm[((size_t)cam * NBLK + blk) * 4 + wave] = bal;
        }
    }
    if (inb) out[OFF_CNT + q] = 1.0f / fmaxf((float)myCount, 1.0f);
    __syncthreads();
    if (tid < NUM_CAMS) ws[WS_OFF + tid * NBLK + blk] = cnt[tid];
}

// (157,6) blocks: wave-reduce partials -> exclusive offset + total; valid bits
// from stored ballot masks (no bev re-read). Writes idx, len, pos table.
__global__ void kBC_indexes(const int* __restrict__ bev, float* __restrict__ out,
                            int* __restrict__ ws, int usePos) {
    const int blk = blockIdx.x;
    const int cam = blockIdx.y;
    const int tid = threadIdx.x;
    const int lane = tid & 63;
    const int wave = tid >> 6;

    const int part = (tid < NBLK) ? ws[WS_OFF + cam * NBLK + tid] : 0;
    int t = part;                       // total over all blocks
    int o = (tid < blk) ? part : 0;     // exclusive offset for this block
    #pragma unroll
    for (int d = 1; d < 64; d <<= 1) {
        t += __shfl_xor(t, d, 64);
        o += __shfl_xor(o, d, 64);
    }
    __shared__ int sT[4], sO[4], waveSums[4];

    u64 mask;
    if (usePos) {
        const u64* wsm = reinterpret_cast<const u64*>(ws + WS_MASK_I);
        mask = wsm[((size_t)cam * NBLK + blk) * 4 + wave];
    } else {
        const int q = blk * 256 + tid;
        bool v = false;
        if (q < NQ) {
            const int4 m = *reinterpret_cast<const int4*>(bev + ((size_t)cam * NQ + q) * 4);
            v = (m.x > 0) | (m.y > 0) | (m.z > 0) | (m.w > 0);
        }
        mask = __ballot(v);
    }
    if (lane == 0) { sT[wave] = t; sO[wave] = o; waveSums[wave] = __popcll(mask); }
    __syncthreads();
    const int total    = sT[0] + sT[1] + sT[2] + sT[3];
    const int blockOff = sO[0] + sO[1] + sO[2] + sO[3];

    if (blk == 0 && tid == 0) {
        const int len = total < MAX_LEN ? total : MAX_LEN;
        ws[WS_LEN + cam] = len;
        out[OFF_LEN + cam] = (float)len;
    }

    const int q = blk * 256 + tid;
    if (q < NQ) {
        int waveOff = 0;
        #pragma unroll
        for (int w = 0; w < 4; ++w)
            if (w < wave) waveOff += waveSums[w];
        const bool v     = (mask >> lane) & 1ull;
        const int prefix = __popcll(mask & ((1ull << lane) - 1ull));
        const int vb  = blockOff + waveOff + prefix;      // valid strictly before q
        const int pos = v ? vb : (total + (q - vb));      // stable partition position
        if (pos < MAX_LEN) out[OFF_IDX + cam * MAX_LEN + pos] = (float)q;
        if (usePos) ws[WS_POS + cam * NQ + q] = (v && vb < MAX_LEN) ? vb : -1;
    }
}

// Persistent grid-stride. Items [0,10000): q-major multicast — read the 1KB
// query row once (aligned float4/lane), build the +2-float shifted chunk via
// shfl so all bulk stores are 16B-ALIGNED (row base is 8 mod 16): lane 0
// stores the two 8B row edges, lanes 1..63 store aligned float4.
// Items [10000,25000): tail rows [len, MAX_LEN) zeroing, same store pattern.
__global__ __launch_bounds__(256) void kGatherQ(const float* __restrict__ query,
                                                const float* __restrict__ refp,
                                                float* __restrict__ out,
                                                const int* __restrict__ ws) {
    const int tid   = threadIdx.x;
    const int group = tid >> 6;
    const int lane  = tid & 63;
    for (int item = blockIdx.x; item < QBLOCKS + TAIL_BLOCKS; item += gridDim.x) {
        if (item < QBLOCKS) {
            const int q = item * 4 + group;   // < NQ
            int pos[NUM_CAMS];
            bool any = false;
            #pragma unroll
            for (int cam = 0; cam < NUM_CAMS; ++cam) {
                const int p = ws[WS_POS + cam * NQ + q];
                pos[cam] = p;
                any |= (p >= 0);
            }
            if (!any) continue;

            const float4 cur = *reinterpret_cast<const float4*>(query + (size_t)q * ED + lane * 4);
            const float pz = __shfl_up(cur.z, 1, 64);   // prev lane's z
            const float pw = __shfl_up(cur.w, 1, 64);   // prev lane's w
            const float tz = __shfl(cur.z, 63, 64);     // src[254]
            const float tw = __shfl(cur.w, 63, 64);     // src[255]
            float4 sh; sh.x = pz; sh.y = pw; sh.z = cur.x; sh.w = cur.y;  // src[4l-2..4l+2)
            f32x2 e0; e0.x = cur.x; e0.y = cur.y;       // src[0..2)   (lane 0 only)
            f32x2 e1; e1.x = tz;   e1.y = tw;           // src[254..256)

            #pragma unroll
            for (int cam = 0; cam < NUM_CAMS; ++cam) {
                const int p = pos[cam];
                if (p >= 0) {
                    float* rowb = out + OFF_Q + ((size_t)cam * MAX_LEN + p) * ED;
                    if (lane > 0) {
                        *reinterpret_cast<float4*>(rowb + 2 + (lane - 1) * 4) = sh;  // 16B aligned
                    } else {
                        *reinterpret_cast<f32x2*>(rowb)       = e0;
                        *reinterpret_cast<f32x2*>(rowb + 254) = e1;
                    }
                    if (lane < 4) {
                        const f32x2 r = *reinterpret_cast<const f32x2*>(refp + ((size_t)cam * NQ + q) * 8 + lane * 2);
                        *reinterpret_cast<f32x2*>(out + OFF_REF + ((size_t)cam * MAX_LEN + p) * 8 + lane * 2) = r;
                    }
                }
            }
        } else {
            const int rowId = (item - QBLOCKS) * 4 + group;
            const int cam   = rowId / MAX_LEN;
            const int j     = rowId - cam * MAX_LEN;
            if (j < ws[WS_LEN + cam]) continue;
            float* rowb = out + OFF_Q + (size_t)rowId * ED;
            const float4 z4 = make_float4(0.f, 0.f, 0.f, 0.f);
            const f32x2  z2 = (f32x2)(0.f);
            if (lane > 0) {
                *reinterpret_cast<float4*>(rowb + 2 + (lane - 1) * 4) = z4;
            } else {
                *reinterpret_cast<f32x2*>(rowb)       = z2;
                *reinterpret_cast<f32x2*>(rowb + 254) = z2;
            }
            if (lane < 4)
                *reinterpret_cast<f32x2*>(out + OFF_REF + (size_t)rowId * 8 + lane * 2) = z2;
        }
    }
}

// Fallback row-major gather (+count_norm) if ws too small for masks+pos table.
__global__ void kGather(const float* __restrict__ query, const float* __restrict__ refp,
                        float* __restrict__ out, const int* __restrict__ ws,
                        const int* __restrict__ bev) {
    const int blk = blockIdx.x;
    const int tid = threadIdx.x;
    if (blk >= GATHER_BLOCKS) {
        const int q = (blk - GATHER_BLOCKS) * 256 + tid;
        if (q < NQ) {
            int cnt = 0;
            #pragma unroll
            for (int cam = 0; cam < NUM_CAMS; ++cam) {
                const int4 m = *reinterpret_cast<const int4*>(bev + ((size_t)cam * NQ + q) * 4);
                cnt += ((m.x > 0) | (m.y > 0) | (m.z > 0) | (m.w > 0)) ? 1 : 0;
            }
            out[OFF_CNT + q] = 1.0f / fmaxf((float)cnt, 1.0f);
        }
        return;
    }
    const int rowId = blk * 4 + (tid >> 6);
    const int lane  = tid & 63;
    const int cam   = rowId / MAX_LEN;
    const int j     = rowId - cam * MAX_LEN;
    const int len   = ws[WS_LEN + cam];

    f32x2 a = (f32x2)(0.f), b = (f32x2)(0.f), r0 = (f32x2)(0.f), r1 = (f32x2)(0.f);
    if (j < len) {
        const int idx = (int)out[OFF_IDX + cam * MAX_LEN + j];
        const float4 vq = *reinterpret_cast<const float4*>(query + (size_t)idx * ED + lane * 4);
        a.x = vq.x; a.y = vq.y;
        b.x = vq.z; b.y = vq.w;
        if (lane < 2) {
            const float4 r = *reinterpret_cast<const float4*>(refp + ((size_t)cam * NQ + idx) * 8 + lane * 4);
            r0.x = r.x; r0.y = r.y;
            r1.x = r.z; r1.y = r.w;
        }
    }
    f32x2* o2 = reinterpret_cast<f32x2*>(out + OFF_Q + (size_t)rowId * ED + lane * 4);
    o2[0] = a;
    o2[1] = b;
    if (lane < 2) {
        f32x2* r2 = reinterpret_cast<f32x2*>(out + OFF_REF + (size_t)rowId * 8 + lane * 4);
        r2[0] = r0;
        r2[1] = r1;
    }
}

extern "C" void kernel_launch(void* const* d_in, const int* in_sizes, int n_in,
                              void* d_out, int out_size, void* d_ws, size_t ws_size,
                              hipStream_t stream) {
    const float* query = (const float*)d_in[0];
    const float* refp  = (const float*)d_in[1];
    const int*   bev   = (const int*)d_in[2];
    float* out = (float*)d_out;
    int*   ws  = (int*)d_ws;
    const int usePos = (ws_size >= (size_t)WS_NEED_BYTES) ? 1 : 0;

    kA_counts<<<NBLK, 256, 0, stream>>>(bev, out, ws, usePos);
    kBC_indexes<<<dim3(NBLK, NUM_CAMS), 256, 0, stream>>>(bev, out, ws, usePos);
    if (usePos) {
        kGatherQ<<<GATHER_GRID, 256, 0, stream>>>(query, refp, out, ws);
    } else {
        kGather<<<GATHER_BLOCKS + CNT_BLOCKS, 256, 0, stream>>>(query, refp, out, ws, bev);
    }
}